// Round 1
// baseline (213.157 us; speedup 1.0000x reference)
//
#include <hip/hip_runtime.h>

// DMoE (PLE/CGC) fused kernel for MI355X (gfx950).
// B=32768, D_IN=256, H=128, N_TASK=2, N_EXP=4, N_SHARE=4.
//
// R8: stall-structure rewrite of R7 (which was dependency/barrier-bound:
// MFMA pipe only ~5.6% absolute-busy, LDS ~30%, HBM 15%).
//  - 2mg x 4ng wave split (64 rows/wave, A[4][8] resident): each ds_read_b128
//    feeds 4 MFMAs instead of 2 -> B-LDS traffic per FLOP halves.
//  - global_load_lds DMA staging (4x w16 + 1x w4 per wave covers the linear
//    4352 B wave chunk): no staging VGPRs, no ds_write phase, no vmcnt(0)
//    drain before barriers.
//  - 3-buffer depth-2 pipeline, counted s_waitcnt vmcnt(5) + raw s_barrier
//    (one barrier/unit, loads stay in flight across barriers).
//  - s_setprio(1) around MFMA clusters.
//  - (512,1): 1 block/CU, LDS ~110 KB. Weight image layout + prep unchanged.

typedef __attribute__((ext_vector_type(8))) short short8;   // 8 x bf16
typedef __attribute__((ext_vector_type(4))) float float4v;  // MFMA C/D + nt loads

#define ROW_US     136        // 128 data + 8 pad (bf16)
#define ROW_B      272
#define UNIT_US    17408      // 128 rows x 136 (half-expert: 128h x 128k)
#define UNIT_B     34816
#define WAVE_B     4352       // UNIT_B / 8 waves
#define WGT_OFF_US 417792     // 24 * 17408
#define COPY_US    421888     // + 16*256 gate ushorts
#define COPY_B     843776

__device__ __forceinline__ unsigned short f2bf(float f) {
  unsigned u = __builtin_bit_cast(unsigned, f);
  u += 0x7FFFu + ((u >> 16) & 1u);   // round-to-nearest-even
  return (unsigned short)(u >> 16);
}

__device__ __forceinline__ int slot2e(int sr, int t) {
  return (sr < 4) ? sr : 4 + t * 4 + (sr - 4);
}

// global -> LDS direct DMA. LDS dest must be wave-uniform; HW adds lane*size.
typedef const __attribute__((address_space(1))) unsigned int GBUF;
typedef __attribute__((address_space(3))) unsigned int LBUF;
__device__ __forceinline__ void gll16(const void* g, void* l) {
  __builtin_amdgcn_global_load_lds((GBUF*)g, (LBUF*)l, 16, 0, 0);
}
__device__ __forceinline__ void gll4(const void* g, void* l) {
  __builtin_amdgcn_global_load_lds((GBUF*)g, (LBUF*)l, 4, 0, 0);
}

// ---------------------------------------------------------------------------
// Prep: WT[c][e][kh] units (128h x 136k bf16) + WgT[16][256] per copy.
// (unchanged from R7 - layout is identical)
__global__ __launch_bounds__(256)
void prep_kernel(const float* __restrict__ Ws,
                 const float* __restrict__ Wt,
                 const float* __restrict__ Wg,
                 unsigned short* __restrict__ WT, int NC) {
  int bid = blockIdx.x;
  int tid = threadIdx.x;
  if (bid < 96) {
    __shared__ float tile[64][65];
    int e  = bid >> 3;
    int kt = (bid >> 1) & 3;   // 64-wide k tile; kh = kt>>1
    int ht = bid & 1;          // h half
    const float* src = (e < 4) ? Ws + ((size_t)e << 15)
                               : Wt + ((size_t)(e - 4) << 15);
    int m = tid & 15, n = tid >> 4;
    #pragma unroll
    for (int i = 0; i < 4; ++i) {   // coalesced read of src[k][h]
      int kl = i * 16 + n;
      float4 v = *(const float4*)&src[(size_t)(kt * 64 + kl) * 128 + ht * 64 + m * 4];
      tile[kl][m * 4 + 0] = v.x;
      tile[kl][m * 4 + 1] = v.y;
      tile[kl][m * 4 + 2] = v.z;
      tile[kl][m * 4 + 3] = v.w;
    }
    __syncthreads();
    #pragma unroll
    for (int i = 0; i < 4; ++i) {
      int hl = i * 16 + n;
      ushort4 o;
      o.x = f2bf(tile[m * 4 + 0][hl]);
      o.y = f2bf(tile[m * 4 + 1][hl]);
      o.z = f2bf(tile[m * 4 + 2][hl]);
      o.w = f2bf(tile[m * 4 + 3][hl]);
      size_t rowbase = (size_t)(e * 2 + (kt >> 1)) * UNIT_US
                     + (size_t)(ht * 64 + hl) * ROW_US + (kt & 1) * 64;
      for (int c = 0; c < NC; ++c) {
        *(ushort4*)&WT[(size_t)c * COPY_US + rowbase + m * 4] = o;
        if ((kt & 1) == 1 && m < 2) {           // zero row pad [128,136)
          ushort4 z = {0, 0, 0, 0};
          *(ushort4*)&WT[(size_t)c * COPY_US + rowbase + 64 + m * 4] = z;
        }
      }
    }
  } else {
    // gate weights WgT[n][256], n = t*8+g
    #pragma unroll
    for (int it = 0; it < 16; ++it) {
      int j = it * 256 + tid;
      int n = j >> 8, k = j & 255;
      int t = n >> 3, g = n & 7;
      unsigned short v = f2bf(Wg[(size_t)(t * 256 + k) * 8 + g]);
      for (int c = 0; c < NC; ++c)
        WT[(size_t)c * COPY_US + WGT_OFF_US + j] = v;
    }
  }
}

// ---------------------------------------------------------------------------
__global__ __launch_bounds__(512, 1)
void dmoe_main(const float* __restrict__ x,
               const unsigned short* __restrict__ WT,
               const float* __restrict__ b_share,
               const float* __restrict__ b_task,
               const float* __restrict__ b_gate,
               float* __restrict__ out, int NC) {
  __shared__ unsigned short Bs0[UNIT_US];   // 34816 B
  __shared__ unsigned short Bs1[UNIT_US];   // 34816 B
  __shared__ unsigned short Bs2[UNIT_US];   // 34816 B  (depth-2 pipeline)
  __shared__ float gatesL[8 * 132];         // [gate-col][row(128)+pad]
  __shared__ float biasLds[8 * 128];        // slot-indexed

  const int tid  = threadIdx.x;
  const int lane = tid & 63;
  const int w    = tid >> 6;    // wave 0..7
  const int col  = lane & 15;
  const int quad = lane >> 4;
  const int mg   = w >> 2;      // rows [mg*64, mg*64+64)
  const int ng   = w & 3;       // h    [ng*32, ng*32+32)
  const int blk  = blockIdx.x;
  const int t    = blk & 1;     // task (== XCD parity: one task per XCD)
  const int rt   = blk >> 1;    // row tile (128 rows)
  const int rot  = (blk >> 3) & 7;

  const char* WTc = (const char*)WT + (size_t)((blk >> 3) % NC) * COPY_B;

  // ---- DMA staging: this wave's linear 4352-B chunk of one unit ----
  auto stage = [&](int un, unsigned short* dst) {
    const char* g = WTc + (size_t)un * UNIT_B + w * WAVE_B;
    char* l = (char*)dst + w * WAVE_B;          // wave-uniform LDS base
    gll16(g + lane * 16,        l);
    gll16(g + 1024 + lane * 16, l + 1024);
    gll16(g + 2048 + lane * 16, l + 2048);
    gll16(g + 3072 + lane * 16, l + 3072);
    gll4 (g + 4096 + lane * 4,  l + 4096);
  };

  // ---- issue first two units' loads first (longest latency) ----
  const int e0 = slot2e(rot, t);
  stage(e0 * 2,     Bs0);
  stage(e0 * 2 + 1, Bs1);

  // ---- A-fragments: 4 m-tiles x 8 k-steps resident (nontemporal x) ----
  short8 A[4][8];
  {
    const float* xb = x + ((size_t)rt * 128 + mg * 64 + col) * 256 + quad * 8;
    #pragma unroll
    for (int mt = 0; mt < 4; ++mt) {
      const float* xr = xb + (size_t)mt * 16 * 256;
      #pragma unroll
      for (int k = 0; k < 8; ++k) {
        float4v u = __builtin_nontemporal_load((const float4v*)(xr + k * 32));
        float4v v = __builtin_nontemporal_load((const float4v*)(xr + k * 32 + 4));
        short8 fr;
        fr[0] = (short)f2bf(u[0]); fr[1] = (short)f2bf(u[1]);
        fr[2] = (short)f2bf(u[2]); fr[3] = (short)f2bf(u[3]);
        fr[4] = (short)f2bf(v[0]); fr[5] = (short)f2bf(v[1]);
        fr[6] = (short)f2bf(v[2]); fr[7] = (short)f2bf(v[3]);
        A[mt][k] = fr;
      }
    }
  }

  // ---- biases -> LDS (slot-indexed: 0..3 shared, 4..7 this task) ----
  for (int i = tid; i < 1024; i += 512) {
    int sr = i >> 7, h = i & 127;
    biasLds[i] = (sr < 4) ? b_share[sr * 128 + h]
                          : b_task[(size_t)(t * 4 + (sr - 4)) * 128 + h];
  }

  // ---- gates: this task's 8 logit cols (cols 8..15 duplicate 0..7) ----
  {
    const unsigned short* WgT = (const unsigned short*)(WTc + WGT_OFF_US * 2);
    const int gr = col & 7;
    const unsigned short* bp = WgT + (size_t)(t * 8 + gr) * 256 + quad * 8;
    short8 Bg[8];
    #pragma unroll
    for (int k = 0; k < 8; ++k) Bg[k] = *(const short8*)(bp + k * 32);
    float bg = b_gate[t * 8 + gr];
    #pragma unroll
    for (int mt = 0; mt < 4; ++mt) {
      float4v ag = {0.f, 0.f, 0.f, 0.f};
      #pragma unroll
      for (int k = 0; k < 8; ++k)
        ag = __builtin_amdgcn_mfma_f32_16x16x32_bf16(A[mt][k], Bg[k], ag, 0, 0, 0);
      #pragma unroll
      for (int r = 0; r < 4; ++r) {
        float vlog = ag[r] + bg;
        float m = vlog;                      // softmax over 8 cols
        m = fmaxf(m, __shfl_xor(m, 1));
        m = fmaxf(m, __shfl_xor(m, 2));
        m = fmaxf(m, __shfl_xor(m, 4));
        float p = __expf(vlog - m);
        float s = p;
        s += __shfl_xor(s, 1);
        s += __shfl_xor(s, 2);
        s += __shfl_xor(s, 4);
        if (ng == 0 && col < 8)
          gatesL[col * 132 + mg * 64 + mt * 16 + quad * 4 + r] = p / s;
      }
    }
  }

  // publish gates/bias ds_writes before the loop's first raw barrier
  asm volatile("s_waitcnt lgkmcnt(0)" ::: "memory");

  // ---- accumulators (task-local) ----
  float tw[4][2][4];   // [mt][nt][r]
  #pragma unroll
  for (int mt = 0; mt < 4; ++mt)
    #pragma unroll
    for (int nt = 0; nt < 2; ++nt)
      #pragma unroll
      for (int r = 0; r < 4; ++r)
        tw[mt][nt][r] = 0.f;

  const int hb = ng * 32;
  const int lrow = (hb + col) * ROW_B + quad * 16;  // per-lane ds_read base
  float4v acc[4][2];

  unsigned short* bA = Bs0;   // read at kh=0
  unsigned short* bB = Bs1;   // read at kh=1
  unsigned short* bC = Bs2;   // issue target at kh=0

  // ---- slot loop: 8 experts x 2 k-halves; depth-2 counted-vmcnt pipeline ----
  #pragma unroll 1
  for (int s = 0; s < 8; ++s) {
    const int sr = (s + rot) & 7;
    const int en = slot2e((s + 1 + rot) & 7, t);

    // ======== kh = 0 : unit e*2 from bA ========
    // outstanding: loads(u) [5] + loads(u+1) [5]  ->  drain loads(u) only
    asm volatile("s_waitcnt vmcnt(5)" ::: "memory");
    __builtin_amdgcn_s_barrier();
    asm volatile("" ::: "memory");
    if (s < 7) stage(en * 2, bC);      // bC last read 2 units ago -> safe
    asm volatile("" ::: "memory");
    #pragma unroll
    for (int mt = 0; mt < 4; ++mt)
      #pragma unroll
      for (int nt = 0; nt < 2; ++nt)
        acc[mt][nt] = (float4v){0.f, 0.f, 0.f, 0.f};
    {
      const char* L = (const char*)bA + lrow;
      __builtin_amdgcn_s_setprio(1);
      #pragma unroll
      for (int kk = 0; kk < 4; ++kk) {
        #pragma unroll
        for (int nt = 0; nt < 2; ++nt) {
          short8 bfr = *(const short8*)(L + nt * (16 * ROW_B) + kk * 64);
          #pragma unroll
          for (int mt = 0; mt < 4; ++mt)
            acc[mt][nt] = __builtin_amdgcn_mfma_f32_16x16x32_bf16(
                A[mt][kk], bfr, acc[mt][nt], 0, 0, 0);
        }
      }
      __builtin_amdgcn_s_setprio(0);
    }

    // ======== kh = 1 : unit e*2+1 from bB ========
    if (s < 7) asm volatile("s_waitcnt vmcnt(5)" ::: "memory");
    else       asm volatile("s_waitcnt vmcnt(0)" ::: "memory");
    __builtin_amdgcn_s_barrier();
    asm volatile("" ::: "memory");
    if (s < 7) stage(en * 2 + 1, bA);  // bA reads finished before this barrier
    asm volatile("" ::: "memory");
    {
      const char* L = (const char*)bB + lrow;
      __builtin_amdgcn_s_setprio(1);
      #pragma unroll
      for (int kk = 0; kk < 4; ++kk) {
        #pragma unroll
        for (int nt = 0; nt < 2; ++nt) {
          short8 bfr = *(const short8*)(L + nt * (16 * ROW_B) + kk * 64);
          #pragma unroll
          for (int mt = 0; mt < 4; ++mt)
            acc[mt][nt] = __builtin_amdgcn_mfma_f32_16x16x32_bf16(
                A[mt][4 + kk], bfr, acc[mt][nt], 0, 0, 0);
        }
      }
      __builtin_amdgcn_s_setprio(0);
    }

    // ---- gated epilogue for this expert ----
    #pragma unroll
    for (int mt = 0; mt < 4; ++mt) {
      int rb = mg * 64 + mt * 16 + quad * 4;
      float4 g = *(const float4*)&gatesL[sr * 132 + rb];
      #pragma unroll
      for (int nt = 0; nt < 2; ++nt) {
        float bias = biasLds[sr * 128 + hb + nt * 16 + col];
        #pragma unroll
        for (int r = 0; r < 4; ++r) {
          float v = fmaxf(acc[mt][nt][r] + bias, 0.f);
          tw[mt][nt][r] += ((const float*)&g)[r] * v;
        }
      }
    }

    // rotate buffers: next kh0 reads bC, next kh1 reads old bA, issue into old bB
    unsigned short* tmp = bA;
    bA = bC; bC = bB; bB = tmp;
  }

  // ---- write towers (nontemporal): out[t][row][h] ----
  #pragma unroll
  for (int mt = 0; mt < 4; ++mt)
    #pragma unroll
    for (int r = 0; r < 4; ++r) {
      size_t row = (size_t)rt * 128 + mg * 64 + mt * 16 + quad * 4 + r;
      float* op = out + ((size_t)t << 22) + row * 128 + hb;
      #pragma unroll
      for (int nt = 0; nt < 2; ++nt)
        __builtin_nontemporal_store(tw[mt][nt][r], op + nt * 16 + col);
    }
}

// ---------------------------------------------------------------------------
extern "C" void kernel_launch(void* const* d_in, const int* in_sizes, int n_in,
                              void* d_out, int out_size, void* d_ws, size_t ws_size,
                              hipStream_t stream) {
  const float* x       = (const float*)d_in[0];
  const float* W_share = (const float*)d_in[1];
  const float* b_share = (const float*)d_in[2];
  const float* W_task  = (const float*)d_in[3];
  const float* b_task  = (const float*)d_in[4];
  const float* W_gate  = (const float*)d_in[5];
  const float* b_gate  = (const float*)d_in[6];
  float* out = (float*)d_out;
  unsigned short* WT = (unsigned short*)d_ws;

  int NC = (int)(ws_size / (size_t)COPY_B);
  if (NC < 1) NC = 1;
  if (NC > 2) NC = 2;

  prep_kernel<<<97, 256, 0, stream>>>(W_share, W_task, W_gate, WT, NC);
  dmoe_main<<<512, 512, 0, stream>>>(x, WT, b_share, b_task, b_gate, out, NC);
}

// Round 2
// 163.497 us; speedup vs baseline: 1.3037x; 1.3037x over previous
//
#include <hip/hip_runtime.h>

// DMoE (PLE/CGC) fused kernel for MI355X (gfx950).
// B=32768, D_IN=256, H=128, N_TASK=2, N_EXP=4, N_SHARE=4.
//
// R9 = R8 schedule (2mg x 4ng geometry, global_load_lds staging, 3-buffer
// depth-2 counted-vmcnt pipeline, setprio) with the three fixes the R8
// counters demanded:
//  - A[4][8] pinned to AGPRs via asm "+a": R8's 200-reg live set spilled to
//    scratch (WRITE_SIZE 33->110 MB). A is MFMA-only -> AGPR resident; arch
//    pressure drops to ~100 regs.
//  - bank-conflict-free LDS: rows now 128 us (256 B), XOR swizzle
//    koff ^= (h&7)<<4 baked into the prep-written weight image (source-side
//    pre-swizzle + swizzled ds_read, linear gll dest). Unit = 32 KB, stage =
//    exactly 4x gll16 per wave.
//  - x loads no longer nontemporal (nt defeated L3 reuse across the task
//    pair; only out stores stay nt).

typedef __attribute__((ext_vector_type(8))) short short8;   // 8 x bf16
typedef __attribute__((ext_vector_type(4))) float float4v;  // MFMA C/D

#define ROW_US     128        // 128 data bf16 (no pad; swizzle handles banks)
#define ROW_B      256
#define UNIT_US    16384      // 128 h-rows x 128 k (half-expert)
#define UNIT_B     32768
#define WAVE_B     4096       // UNIT_B / 8 waves
#define WGT_OFF_US 393216     // 24 * 16384
#define COPY_US    397312     // + 16*256 gate ushorts
#define COPY_B     794624

__device__ __forceinline__ unsigned short f2bf(float f) {
  unsigned u = __builtin_bit_cast(unsigned, f);
  u += 0x7FFFu + ((u >> 16) & 1u);   // round-to-nearest-even
  return (unsigned short)(u >> 16);
}

__device__ __forceinline__ int slot2e(int sr, int t) {
  return (sr < 4) ? sr : 4 + t * 4 + (sr - 4);
}

// global -> LDS direct DMA. LDS dest is wave-uniform; HW adds lane*size.
typedef const __attribute__((address_space(1))) unsigned int GBUF;
typedef __attribute__((address_space(3))) unsigned int LBUF;
__device__ __forceinline__ void gll16(const void* g, void* l) {
  __builtin_amdgcn_global_load_lds((GBUF*)g, (LBUF*)l, 16, 0, 0);
}

// ---------------------------------------------------------------------------
// Prep: WT[c][unit] images, 128h x 128k bf16 per unit, k-bytes XOR-swizzled
// by ((h&7)<<4) so main-kernel ds_read_b128 is bank-conflict-free.
// + WgT[16][256] gate weights per copy (unswizzled).
__global__ __launch_bounds__(256)
void prep_kernel(const float* __restrict__ Ws,
                 const float* __restrict__ Wt,
                 const float* __restrict__ Wg,
                 unsigned short* __restrict__ WT, int NC) {
  int bid = blockIdx.x;
  int tid = threadIdx.x;
  if (bid < 96) {
    __shared__ float tile[64][65];
    int e  = bid >> 3;
    int kt = (bid >> 1) & 3;   // 64-wide k tile; unit k-half = kt&1
    int ht = bid & 1;          // h half
    const float* src = (e < 4) ? Ws + ((size_t)e << 15)
                               : Wt + ((size_t)(e - 4) << 15);
    int m = tid & 15, n = tid >> 4;
    #pragma unroll
    for (int i = 0; i < 4; ++i) {   // coalesced read of src[k][h]
      int kl = i * 16 + n;
      float4 v = *(const float4*)&src[(size_t)(kt * 64 + kl) * 128 + ht * 64 + m * 4];
      tile[kl][m * 4 + 0] = v.x;
      tile[kl][m * 4 + 1] = v.y;
      tile[kl][m * 4 + 2] = v.z;
      tile[kl][m * 4 + 3] = v.w;
    }
    __syncthreads();
    #pragma unroll
    for (int i = 0; i < 4; ++i) {
      int hl = i * 16 + n;
      ushort4 o;
      o.x = f2bf(tile[m * 4 + 0][hl]);
      o.y = f2bf(tile[m * 4 + 1][hl]);
      o.z = f2bf(tile[m * 4 + 2][hl]);
      o.w = f2bf(tile[m * 4 + 3][hl]);
      // k-offset within row (ushorts), XOR-swizzled: byte ^= (h&7)<<4
      int kofs = (((kt & 1) * 64) + m * 4) ^ ((hl & 7) << 3);
      size_t base = (size_t)(e * 2 + (kt >> 1)) * UNIT_US
                  + (size_t)(ht * 64 + hl) * ROW_US + kofs;
      for (int c = 0; c < NC; ++c)
        *(ushort4*)&WT[(size_t)c * COPY_US + base] = o;
    }
  } else {
    // gate weights WgT[n][256], n = t*8+g
    #pragma unroll
    for (int it = 0; it < 16; ++it) {
      int j = it * 256 + tid;
      int n = j >> 8, k = j & 255;
      int t = n >> 3, g = n & 7;
      unsigned short v = f2bf(Wg[(size_t)(t * 256 + k) * 8 + g]);
      for (int c = 0; c < NC; ++c)
        WT[(size_t)c * COPY_US + WGT_OFF_US + j] = v;
    }
  }
}

// ---------------------------------------------------------------------------
__global__ __launch_bounds__(512, 1)
void dmoe_main(const float* __restrict__ x,
               const unsigned short* __restrict__ WT,
               const float* __restrict__ b_share,
               const float* __restrict__ b_task,
               const float* __restrict__ b_gate,
               float* __restrict__ out, int NC) {
  __shared__ unsigned short Bs0[UNIT_US];   // 32768 B
  __shared__ unsigned short Bs1[UNIT_US];   // 32768 B
  __shared__ unsigned short Bs2[UNIT_US];   // 32768 B (depth-2 pipeline)
  __shared__ float gatesL[8 * 132];         // [gate-col][row(128)+pad]
  __shared__ float biasLds[8 * 128];        // slot-indexed

  const int tid  = threadIdx.x;
  const int lane = tid & 63;
  const int w    = tid >> 6;    // wave 0..7
  const int col  = lane & 15;
  const int quad = lane >> 4;
  const int mg   = w >> 2;      // rows [mg*64, mg*64+64)
  const int ng   = w & 3;       // h    [ng*32, ng*32+32)
  const int blk  = blockIdx.x;
  const int t    = blk & 1;     // task (== XCD parity: one task per XCD)
  const int rt   = blk >> 1;    // row tile (128 rows)
  const int rot  = (blk >> 3) & 7;

  const char* WTc = (const char*)WT + (size_t)((blk >> 3) % NC) * COPY_B;

  // ---- DMA staging: this wave's linear 4096-B chunk of one unit ----
  auto stage = [&](int un, unsigned short* dst) {
    const char* g = WTc + (size_t)un * UNIT_B + w * WAVE_B;
    char* l = (char*)dst + w * WAVE_B;          // wave-uniform LDS base
    gll16(g + lane * 16,        l);
    gll16(g + 1024 + lane * 16, l + 1024);
    gll16(g + 2048 + lane * 16, l + 2048);
    gll16(g + 3072 + lane * 16, l + 3072);
  };

  // ---- issue first two units' loads first (longest latency) ----
  const int e0 = slot2e(rot, t);
  stage(e0 * 2,     Bs0);
  stage(e0 * 2 + 1, Bs1);

  // ---- A-fragments: 4 m-tiles x 8 k-steps resident; pin into AGPRs ----
  short8 A[4][8];
  {
    const float* xb = x + ((size_t)rt * 128 + mg * 64 + col) * 256 + quad * 8;
    #pragma unroll
    for (int mt = 0; mt < 4; ++mt) {
      const float* xr = xb + (size_t)mt * 16 * 256;
      #pragma unroll
      for (int k = 0; k < 8; ++k) {
        float4v u = *(const float4v*)(xr + k * 32);
        float4v v = *(const float4v*)(xr + k * 32 + 4);
        short8 fr;
        fr[0] = (short)f2bf(u[0]); fr[1] = (short)f2bf(u[1]);
        fr[2] = (short)f2bf(u[2]); fr[3] = (short)f2bf(u[3]);
        fr[4] = (short)f2bf(v[0]); fr[5] = (short)f2bf(v[1]);
        fr[6] = (short)f2bf(v[2]); fr[7] = (short)f2bf(v[3]);
        A[mt][k] = fr;
        asm volatile("" : "+a"(A[mt][k]));   // force AGPR residency
      }
    }
  }

  // ---- biases -> LDS (slot-indexed: 0..3 shared, 4..7 this task) ----
  for (int i = tid; i < 1024; i += 512) {
    int sr = i >> 7, h = i & 127;
    biasLds[i] = (sr < 4) ? b_share[sr * 128 + h]
                          : b_task[(size_t)(t * 4 + (sr - 4)) * 128 + h];
  }

  // ---- gates: this task's 8 logit cols (cols 8..15 duplicate 0..7) ----
  {
    const unsigned short* WgT = (const unsigned short*)(WTc + WGT_OFF_US * 2);
    const int gr = col & 7;
    const unsigned short* bp = WgT + (size_t)(t * 8 + gr) * 256 + quad * 8;
    short8 Bg[8];
    #pragma unroll
    for (int k = 0; k < 8; ++k) Bg[k] = *(const short8*)(bp + k * 32);
    float bg = b_gate[t * 8 + gr];
    #pragma unroll
    for (int mt = 0; mt < 4; ++mt) {
      float4v ag = {0.f, 0.f, 0.f, 0.f};
      #pragma unroll
      for (int k = 0; k < 8; ++k)
        ag = __builtin_amdgcn_mfma_f32_16x16x32_bf16(A[mt][k], Bg[k], ag, 0, 0, 0);
      #pragma unroll
      for (int r = 0; r < 4; ++r) {
        float vlog = ag[r] + bg;
        float m = vlog;                      // softmax over 8 cols
        m = fmaxf(m, __shfl_xor(m, 1));
        m = fmaxf(m, __shfl_xor(m, 2));
        m = fmaxf(m, __shfl_xor(m, 4));
        float p = __expf(vlog - m);
        float s = p;
        s += __shfl_xor(s, 1);
        s += __shfl_xor(s, 2);
        s += __shfl_xor(s, 4);
        if (ng == 0 && col < 8)
          gatesL[col * 132 + mg * 64 + mt * 16 + quad * 4 + r] = p / s;
      }
    }
  }

  // publish gates/bias ds_writes before the loop's first raw barrier
  asm volatile("s_waitcnt lgkmcnt(0)" ::: "memory");

  // ---- accumulators (task-local) ----
  float tw[4][2][4];   // [mt][nt][r]
  #pragma unroll
  for (int mt = 0; mt < 4; ++mt)
    #pragma unroll
    for (int nt = 0; nt < 2; ++nt)
      #pragma unroll
      for (int r = 0; r < 4; ++r)
        tw[mt][nt][r] = 0.f;

  const int hb = ng * 32;
  const int c7 = col & 7;
  const int rowbyte = (hb + col) * ROW_B;   // + nt*16*ROW_B + swizzled koff
  float4v acc[4][2];

  unsigned short* bA = Bs0;   // read at kh=0
  unsigned short* bB = Bs1;   // read at kh=1
  unsigned short* bC = Bs2;   // issue target at kh=0

  // ---- slot loop: 8 experts x 2 k-halves; depth-2 counted-vmcnt pipeline ----
  #pragma unroll 1
  for (int s = 0; s < 8; ++s) {
    const int sr = (s + rot) & 7;
    const int en = slot2e((s + 1 + rot) & 7, t);

    // ======== kh = 0 : unit e*2 from bA ========
    // steady state: 8 outstanding loads -> retire the oldest 4 (this unit)
    asm volatile("s_waitcnt vmcnt(4)" ::: "memory");
    __builtin_amdgcn_s_barrier();
    asm volatile("" ::: "memory");
    if (s < 7) stage(en * 2, bC);      // bC last read 2 units ago -> safe
    asm volatile("" ::: "memory");
    #pragma unroll
    for (int mt = 0; mt < 4; ++mt)
      #pragma unroll
      for (int nt = 0; nt < 2; ++nt)
        acc[mt][nt] = (float4v){0.f, 0.f, 0.f, 0.f};
    {
      const char* L = (const char*)bA;
      __builtin_amdgcn_s_setprio(1);
      #pragma unroll
      for (int kk = 0; kk < 4; ++kk) {
        #pragma unroll
        for (int nt = 0; nt < 2; ++nt) {
          short8 bfr = *(const short8*)(L + rowbyte + nt * (16 * ROW_B)
                                        + ((((kk << 2) + quad) ^ c7) << 4));
          #pragma unroll
          for (int mt = 0; mt < 4; ++mt)
            acc[mt][nt] = __builtin_amdgcn_mfma_f32_16x16x32_bf16(
                A[mt][kk], bfr, acc[mt][nt], 0, 0, 0);
        }
      }
      __builtin_amdgcn_s_setprio(0);
    }

    // ======== kh = 1 : unit e*2+1 from bB ========
    if (s < 7) asm volatile("s_waitcnt vmcnt(4)" ::: "memory");
    else       asm volatile("s_waitcnt vmcnt(0)" ::: "memory");
    __builtin_amdgcn_s_barrier();
    asm volatile("" ::: "memory");
    if (s < 7) stage(en * 2 + 1, bA);  // bA reads finished before this barrier
    asm volatile("" ::: "memory");
    {
      const char* L = (const char*)bB;
      __builtin_amdgcn_s_setprio(1);
      #pragma unroll
      for (int kk = 0; kk < 4; ++kk) {
        #pragma unroll
        for (int nt = 0; nt < 2; ++nt) {
          short8 bfr = *(const short8*)(L + rowbyte + nt * (16 * ROW_B)
                                        + ((((kk << 2) + quad) ^ c7) << 4));
          #pragma unroll
          for (int mt = 0; mt < 4; ++mt)
            acc[mt][nt] = __builtin_amdgcn_mfma_f32_16x16x32_bf16(
                A[mt][4 + kk], bfr, acc[mt][nt], 0, 0, 0);
        }
      }
      __builtin_amdgcn_s_setprio(0);
    }

    // ---- gated epilogue for this expert ----
    #pragma unroll
    for (int mt = 0; mt < 4; ++mt) {
      int rb = mg * 64 + mt * 16 + quad * 4;
      float4 g = *(const float4*)&gatesL[sr * 132 + rb];
      #pragma unroll
      for (int nt = 0; nt < 2; ++nt) {
        float bias = biasLds[sr * 128 + hb + nt * 16 + col];
        #pragma unroll
        for (int r = 0; r < 4; ++r) {
          float v = fmaxf(acc[mt][nt][r] + bias, 0.f);
          tw[mt][nt][r] += ((const float*)&g)[r] * v;
        }
      }
    }

    // rotate buffers: next kh0 reads bC, next kh1 reads old bA, issue into old bB
    unsigned short* tmp = bA;
    bA = bC; bC = bB; bB = tmp;
  }

  // ---- write towers (nontemporal): out[t][row][h] ----
  #pragma unroll
  for (int mt = 0; mt < 4; ++mt)
    #pragma unroll
    for (int r = 0; r < 4; ++r) {
      size_t row = (size_t)rt * 128 + mg * 64 + mt * 16 + quad * 4 + r;
      float* op = out + ((size_t)t << 22) + row * 128 + hb;
      #pragma unroll
      for (int nt = 0; nt < 2; ++nt)
        __builtin_nontemporal_store(tw[mt][nt][r], op + nt * 16 + col);
    }
}

// ---------------------------------------------------------------------------
extern "C" void kernel_launch(void* const* d_in, const int* in_sizes, int n_in,
                              void* d_out, int out_size, void* d_ws, size_t ws_size,
                              hipStream_t stream) {
  const float* x       = (const float*)d_in[0];
  const float* W_share = (const float*)d_in[1];
  const float* b_share = (const float*)d_in[2];
  const float* W_task  = (const float*)d_in[3];
  const float* b_task  = (const float*)d_in[4];
  const float* W_gate  = (const float*)d_in[5];
  const float* b_gate  = (const float*)d_in[6];
  float* out = (float*)d_out;
  unsigned short* WT = (unsigned short*)d_ws;

  int NC = (int)(ws_size / (size_t)COPY_B);
  if (NC < 1) NC = 1;
  if (NC > 2) NC = 2;

  prep_kernel<<<97, 256, 0, stream>>>(W_share, W_task, W_gate, WT, NC);
  dmoe_main<<<512, 512, 0, stream>>>(x, WT, b_share, b_task, b_gate, out, NC);
}